// Round 1
// baseline (324.356 us; speedup 1.0000x reference)
//
#include <hip/hip_runtime.h>
#include <cmath>

// Problem constants (B=16, C=1024, D=768 derived from in_sizes; fixed for this problem)
static constexpr int kC = 1024;
static constexpr int kD = 768;
static constexpr int kThreads = 256;
static constexpr int kEPT = kC / kThreads; // 4 elements per thread
static constexpr float kTauInv = 10.0f;    // 1/TAU

// float -> sortable unsigned key (monotone: a > b  <=>  fkey(a) > fkey(b)), no NaNs expected
__device__ __forceinline__ unsigned fkey(float f) {
  unsigned b = __float_as_uint(f);
  return (b & 0x80000000u) ? ~b : (b | 0x80000000u);
}

// ---- block reductions over 256 threads (4 waves of 64) ----
__device__ __forceinline__ float block_sum(float v, volatile float* sc) {
  #pragma unroll
  for (int off = 32; off > 0; off >>= 1) v += __shfl_down(v, off, 64);
  int wv = threadIdx.x >> 6;
  int ln = threadIdx.x & 63;
  __syncthreads();
  if (ln == 0) sc[wv] = v;
  __syncthreads();
  return sc[0] + sc[1] + sc[2] + sc[3];
}

__device__ __forceinline__ float block_max(float v, volatile float* sc) {
  #pragma unroll
  for (int off = 32; off > 0; off >>= 1) v = fmaxf(v, __shfl_down(v, off, 64));
  int wv = threadIdx.x >> 6;
  int ln = threadIdx.x & 63;
  __syncthreads();
  if (ln == 0) sc[wv] = v;
  __syncthreads();
  return fmaxf(fmaxf(sc[0], sc[1]), fmaxf(sc[2], sc[3]));
}

// k-th largest key among the block's kEPT-per-thread keys, via 32-step binary search.
// Returns the same value on all threads.
__device__ unsigned kth_largest_key(const unsigned* mykey, int kth, volatile float* sc) {
  unsigned lo = 0u, hi = 0xFFFFFFFFu;
  while (lo < hi) {
    unsigned mid = lo + ((hi - lo) >> 1);
    float c_ = 0.f;
    #pragma unroll
    for (int k = 0; k < kEPT; ++k) c_ += (mykey[k] > mid) ? 1.f : 0.f;
    float cnt = block_sum(c_, sc);
    if (cnt >= (float)kth) lo = mid + 1u; else hi = mid;
  }
  return lo;
}

// ---- kernel 1: normalize prototypes: pn[e,:] = p[e,:] / max(||p[e,:]||, 1e-12) ----
__global__ void norm_proto_kernel(const float* __restrict__ p, float* __restrict__ pn) {
  __shared__ float sc[8];
  int e = blockIdx.x;
  const float* row = p + (size_t)e * kD;
  int t = threadIdx.x;
  float x0 = row[t], x1 = row[t + 256], x2 = row[t + 512];
  float ss = block_sum(x0 * x0 + x1 * x1 + x2 * x2, sc);
  float scale = 1.0f / fmaxf(sqrtf(ss), 1e-12f);
  float* out = pn + (size_t)e * kD;
  out[t] = x0 * scale; out[t + 256] = x1 * scale; out[t + 512] = x2 * scale;
}

// ---- kernel 2: per-batch random-negative mask (top-K_rand of masked rand scores) + pos counts ----
__global__ void rand_select_kernel(const int* __restrict__ targets,
                                   const float* __restrict__ rs,
                                   int* __restrict__ rmask,
                                   float* __restrict__ poscnt,
                                   int K_rand) {
  __shared__ unsigned keys[kC];
  __shared__ float sc[8];
  int b = blockIdx.x;
  int t = threadIdx.x;
  unsigned mykey[kEPT];
  float cp = 0.f;
  #pragma unroll
  for (int k = 0; k < kEPT; ++k) {
    int e = t + kThreads * k;
    int tg = targets[b * kC + e];
    cp += (tg != 0) ? 1.f : 0.f;
    float v = (tg == 0) ? rs[b * kC + e] : -INFINITY;
    unsigned kk = fkey(v);
    mykey[k] = kk;
    keys[e] = kk;
  }
  float pc = block_sum(cp, sc);
  if (t == 0) poscnt[b] = fmaxf(pc, 1.f);

  unsigned thr = kth_largest_key(mykey, K_rand, sc);
  float cg = 0.f, ce = 0.f;
  #pragma unroll
  for (int k = 0; k < kEPT; ++k) {
    cg += (mykey[k] > thr) ? 1.f : 0.f;
    ce += (mykey[k] == thr) ? 1.f : 0.f;
  }
  int n_g = (int)block_sum(cg, sc);
  int n_eq = (int)block_sum(ce, sc);
  int need = K_rand - n_g;
  bool take_all_eq = (n_eq <= need);  // common case: no tie conflict
  #pragma unroll
  for (int k = 0; k < kEPT; ++k) {
    int e = t + kThreads * k;
    int sel = 0;
    if (mykey[k] > thr) sel = 1;
    else if (mykey[k] == thr) {
      if (take_all_eq) sel = 1;
      else {  // rare: true tie -> lowest-index-first like lax.top_k
        int r = 0;
        for (int j = 0; j < e; ++j) r += (keys[j] == thr) ? 1 : 0;
        sel = (r < need) ? 1 : 0;
      }
    }
    rmask[b * kC + e] = sel;
  }
}

// ---- kernel 3: one block per (b,c); active only for positive anchors ----
__global__ void __launch_bounds__(kThreads)
anchor_kernel(const float* __restrict__ f, const float* __restrict__ pn,
              const int* __restrict__ targets, const int* __restrict__ rmask,
              const float* __restrict__ poscnt, float* __restrict__ out,
              int B, int K_hard) {
  int b = blockIdx.x / kC;
  int c = blockIdx.x % kC;
  if (targets[b * kC + c] == 0) return;  // uniform across block

  __shared__ __align__(16) float fl[kD];
  __shared__ float sims[kC];
  __shared__ float sc[8];
  int t = threadIdx.x;

  // normalize f[b,c,:] into LDS
  const float* frow = f + ((size_t)(b * kC + c)) * kD;
  float x0 = frow[t], x1 = frow[t + 256], x2 = frow[t + 512];
  float ss = block_sum(x0 * x0 + x1 * x1 + x2 * x2, sc);
  float scale = 1.0f / fmaxf(sqrtf(ss), 1e-12f);
  fl[t] = x0 * scale; fl[t + 256] = x1 * scale; fl[t + 512] = x2 * scale;
  __syncthreads();

  // wave-cooperative GEMV: wave w computes columns [w*256, w*256+256)
  int wv = t >> 6, ln = t & 63;
  const float4* fl4 = reinterpret_cast<const float4*>(fl);
  const float4* pn4 = reinterpret_cast<const float4*>(pn);
  for (int e = wv * 256; e < wv * 256 + 256; ++e) {
    const float4* row = pn4 + (size_t)e * (kD / 4);
    float acc = 0.f;
    #pragma unroll
    for (int i = 0; i < kD / 4 / 64; ++i) {  // 3 iterations
      float4 a = row[ln + 64 * i];
      float4 bb = fl4[ln + 64 * i];
      acc = fmaf(a.x, bb.x, acc);
      acc = fmaf(a.y, bb.y, acc);
      acc = fmaf(a.z, bb.z, acc);
      acc = fmaf(a.w, bb.w, acc);
    }
    #pragma unroll
    for (int off = 32; off > 0; off >>= 1) acc += __shfl_down(acc, off, 64);
    if (ln == 0) sims[e] = acc * kTauInv;  // tempered sims
  }
  __syncthreads();

  float pos = sims[c];
  __syncthreads();

  // mask negatives in-place (column c is positive -> masked out, matching reference)
  float mv[kEPT];
  unsigned mk[kEPT];
  #pragma unroll
  for (int k = 0; k < kEPT; ++k) {
    int e = t + kThreads * k;
    int tg = targets[b * kC + e];
    float v = (tg == 0) ? sims[e] : -INFINITY;
    mv[k] = v;
    mk[k] = fkey(v);
  }
  __syncthreads();
  #pragma unroll
  for (int k = 0; k < kEPT; ++k) sims[t + kThreads * k] = mv[k];
  __syncthreads();

  // row max over masked values (for stable LSE); also >= every selected value
  float mx = fmaxf(fmaxf(mv[0], mv[1]), fmaxf(mv[2], mv[3]));
  float m = block_max(mx, sc);

  // hard negatives: top-K_hard of masked sims (ordering identical raw vs tempered)
  unsigned thr = kth_largest_key(mk, K_hard, sc);
  float cg = 0.f, ce = 0.f;
  #pragma unroll
  for (int k = 0; k < kEPT; ++k) {
    cg += (mk[k] > thr) ? 1.f : 0.f;
    ce += (mk[k] == thr) ? 1.f : 0.f;
  }
  int n_g = (int)block_sum(cg, sc);
  int n_eq = (int)block_sum(ce, sc);
  int need = K_hard - n_g;
  bool take_all_eq = (n_eq <= need);

  // sum exp over hard set + rand set (duplicates counted twice, as in reference concat)
  float s = 0.f;
  #pragma unroll
  for (int k = 0; k < kEPT; ++k) {
    int e = t + kThreads * k;
    float ev = (mv[k] == -INFINITY) ? 0.f : expf(mv[k] - m);
    bool selh = (mk[k] > thr);
    if (!selh && mk[k] == thr) {
      if (take_all_eq) selh = true;
      else {
        int r = 0;
        for (int j = 0; j < e; ++j) r += (fkey(sims[j]) == thr) ? 1 : 0;
        selh = (r < need);
      }
    }
    if (selh) s += ev;
    if (rmask[b * kC + e]) s += ev;
  }
  float S = block_sum(s, sc);

  if (t == 0) {
    float lse = m + logf(S);
    float x = lse - pos;                     // per_anchor = softplus(lse - pos)
    float pa = (x > 0.f) ? x + log1pf(expf(-x)) : log1pf(expf(x));
    atomicAdd(out, pa / (poscnt[b] * (float)B));
  }
}

extern "C" void kernel_launch(void* const* d_in, const int* in_sizes, int n_in,
                              void* d_out, int out_size, void* d_ws, size_t ws_size,
                              hipStream_t stream) {
  const float* f = (const float*)d_in[0];       // (B,C,D) fp32
  const float* proto = (const float*)d_in[1];   // (C,D)   fp32
  const int* targets = (const int*)d_in[2];     // (B,C)   int
  const float* rs = (const float*)d_in[3];      // (B,C)   fp32

  const int D = in_sizes[0] / in_sizes[2];      // 768
  const int C = in_sizes[1] / D;                // 1024
  const int B = in_sizes[2] / C;                // 16
  const int K = C - 1;
  const int K_hard = (int)(K * 0.3);            // 306
  const int K_rand = K - K_hard;                // 717

  // workspace layout
  char* ws = (char*)d_ws;
  float* pn = (float*)ws;                                        // C*D floats (normalized protos)
  int* rmask = (int*)(ws + sizeof(float) * (size_t)C * D);       // B*C ints
  float* poscnt = (float*)((char*)rmask + sizeof(int) * (size_t)B * C);  // B floats

  float* out = (float*)d_out;
  hipMemsetAsync(out, 0, sizeof(float), stream);

  norm_proto_kernel<<<C, kThreads, 0, stream>>>(proto, pn);
  rand_select_kernel<<<B, kThreads, 0, stream>>>(targets, rs, rmask, poscnt, K_rand);
  anchor_kernel<<<B * C, kThreads, 0, stream>>>(f, pn, targets, rmask, poscnt, out, B, K_hard);
}

// Round 2
// 197.359 us; speedup vs baseline: 1.6435x; 1.6435x over previous
//
#include <hip/hip_runtime.h>
#include <cmath>

static constexpr int kC = 1024;
static constexpr int kD = 768;
static constexpr int kThreads = 256;
static constexpr int kEPT = kC / kThreads;   // 4
static constexpr float kTauInv = 10.0f;
static constexpr int kKS = kD / 32;          // 24 K-steps
static constexpr int kSimsStride = 1028;     // floats; %32==4 -> conflict-free MFMA epilogue writes

typedef __attribute__((ext_vector_type(8))) short short8_t;
typedef __attribute__((ext_vector_type(4))) float f32x4_t;
union I4S8 { int4 i; short8_t s; };

__device__ __forceinline__ unsigned fkey(float f) {
  unsigned b = __float_as_uint(f);
  return (b & 0x80000000u) ? ~b : (b | 0x80000000u);
}

// round-to-nearest-even fp32 -> bf16 bits
__device__ __forceinline__ unsigned bfr(float x) {
  unsigned u = __float_as_uint(x);
  return (u + 0x7fffu + ((u >> 16) & 1u)) >> 16;
}

// ---- block reductions over 256 threads (4 waves of 64) ----
__device__ __forceinline__ float block_sum(float v, volatile float* sc) {
  #pragma unroll
  for (int off = 32; off > 0; off >>= 1) v += __shfl_down(v, off, 64);
  int wv = threadIdx.x >> 6;
  int ln = threadIdx.x & 63;
  __syncthreads();
  if (ln == 0) sc[wv] = v;
  __syncthreads();
  return sc[0] + sc[1] + sc[2] + sc[3];
}

__device__ unsigned kth_largest_key_block(const unsigned* mykey, int kth, volatile float* sc) {
  unsigned lo = 0u, hi = 0xFFFFFFFFu;
  while (lo < hi) {
    unsigned mid = lo + ((hi - lo) >> 1);
    float c_ = 0.f;
    #pragma unroll
    for (int k = 0; k < kEPT; ++k) c_ += (mykey[k] > mid) ? 1.f : 0.f;
    float cnt = block_sum(c_, sc);
    if (cnt >= (float)kth) lo = mid + 1u; else hi = mid;
  }
  return lo;
}

// ---- K1: normalize prototypes -> bf16 in MFMA B-fragment layout ----
// pnf layout (int4 units): index = (gnt*24 + ks)*64 + ln
//   holds pn[col = gnt*16 + (ln&15)][k = ks*32 + (ln>>4)*8 .. +8]
__global__ void __launch_bounds__(kThreads) proto_pack_kernel(
    const float* __restrict__ p, int4* __restrict__ pnf) {
  __shared__ float scl[16];
  int n0 = blockIdx.x * 16;
  int t = threadIdx.x;
  int r = t >> 4, part = t & 15;
  const float4* row4 = (const float4*)(p + (size_t)(n0 + r) * kD) + part * 12;
  float ss = 0.f;
  #pragma unroll
  for (int i = 0; i < 12; ++i) {
    float4 v = row4[i];
    ss += v.x * v.x + v.y * v.y + v.z * v.z + v.w * v.w;
  }
  #pragma unroll
  for (int off = 8; off > 0; off >>= 1) ss += __shfl_xor(ss, off, 16);
  if (part == 0) scl[r] = 1.0f / fmaxf(sqrtf(ss), 1e-12f);
  __syncthreads();
  // 1536 16B-chunks per block; 6 per thread, coalesced stores
  #pragma unroll
  for (int i = 0; i < 6; ++i) {
    int chunk = i * 256 + t;
    int ks = chunk >> 6;
    int ln = chunk & 63;
    int col = ln & 15;
    int k0 = ks * 32 + (ln >> 4) * 8;
    const float* src = p + (size_t)(n0 + col) * kD + k0;
    float s = scl[col];
    float4 a = *(const float4*)(src);
    float4 b = *(const float4*)(src + 4);
    int4 pk;
    pk.x = bfr(a.x * s) | (bfr(a.y * s) << 16);
    pk.y = bfr(a.z * s) | (bfr(a.w * s) << 16);
    pk.z = bfr(b.x * s) | (bfr(b.y * s) << 16);
    pk.w = bfr(b.z * s) | (bfr(b.w * s) << 16);
    pnf[(size_t)((blockIdx.x * kKS + ks) << 6) + ln] = pk;
  }
}

// ---- K2: rand mask + pos counts + compact positive anchors ----
__global__ void __launch_bounds__(kThreads) rand_select_kernel(
    const int* __restrict__ targets, const float* __restrict__ rs,
    int* __restrict__ rmask, float* __restrict__ poscnt,
    int* __restrict__ npos, int* __restrict__ alist, int K_rand) {
  __shared__ unsigned keys[kC];
  __shared__ float sc[8];
  int b = blockIdx.x;
  int t = threadIdx.x;
  unsigned mykey[kEPT];
  float cp = 0.f;
  #pragma unroll
  for (int k = 0; k < kEPT; ++k) {
    int e = t + kThreads * k;
    int tg = targets[b * kC + e];
    cp += (tg != 0) ? 1.f : 0.f;
    if (tg != 0) {
      int idx = atomicAdd(npos, 1);
      alist[idx] = b * kC + e;   // flat row index == (b<<10)|c
    }
    float v = (tg == 0) ? rs[b * kC + e] : -INFINITY;
    unsigned kk = fkey(v);
    mykey[k] = kk;
    keys[e] = kk;
  }
  float pc = block_sum(cp, sc);
  if (t == 0) poscnt[b] = fmaxf(pc, 1.f);

  unsigned thr = kth_largest_key_block(mykey, K_rand, sc);
  float cg = 0.f, ce = 0.f;
  #pragma unroll
  for (int k = 0; k < kEPT; ++k) {
    cg += (mykey[k] > thr) ? 1.f : 0.f;
    ce += (mykey[k] == thr) ? 1.f : 0.f;
  }
  int n_g = (int)block_sum(cg, sc);
  int n_eq = (int)block_sum(ce, sc);
  int need = K_rand - n_g;
  bool take_all_eq = (n_eq <= need);
  #pragma unroll
  for (int k = 0; k < kEPT; ++k) {
    int e = t + kThreads * k;
    int sel = 0;
    if (mykey[k] > thr) sel = 1;
    else if (mykey[k] == thr) {
      if (take_all_eq) sel = 1;
      else {
        int r = 0;
        for (int j = 0; j < e; ++j) r += (keys[j] == thr) ? 1 : 0;
        sel = (r < need) ? 1 : 0;
      }
    }
    rmask[b * kC + e] = sel;
  }
}

// ---- K3: fused MFMA GEMM (16 anchors x 1024 cols x 768) + wave-local epilogue ----
__global__ void __launch_bounds__(kThreads) gemm_epi_kernel(
    const float* __restrict__ f, const int4* __restrict__ pnf,
    const int* __restrict__ targets, const int* __restrict__ rmask,
    const float* __restrict__ poscnt, const int* __restrict__ npos_p,
    const int* __restrict__ alist, float* __restrict__ out,
    int B, int K_hard) {
  __shared__ __align__(16) char smem[kSimsStride * 16 * 4];  // 65792 B: a_frag (24KB) then sims alias
  __shared__ int rowbc[16];
  __shared__ float rowscl[16];

  int npos = *npos_p;
  int m0 = blockIdx.x * 16;
  if (m0 >= npos) return;
  int t = threadIdx.x;

  if (t < 16) rowbc[t] = (m0 + t < npos) ? alist[m0 + t] : -1;
  __syncthreads();

  // ---- phase A: row norms ----
  {
    int r = t >> 4, part = t & 15;
    int bc = rowbc[r];
    int bcu = (bc < 0) ? rowbc[0] : bc;
    const float4* f4 = (const float4*)(f + (size_t)bcu * kD) + part * 12;
    float ss = 0.f;
    #pragma unroll
    for (int i = 0; i < 12; ++i) {
      float4 v = f4[i];
      ss += v.x * v.x + v.y * v.y + v.z * v.z + v.w * v.w;
    }
    #pragma unroll
    for (int off = 8; off > 0; off >>= 1) ss += __shfl_xor(ss, off, 16);
    if (part == 0) rowscl[r] = (bc < 0) ? 0.f : 1.0f / fmaxf(sqrtf(ss), 1e-12f);
  }
  __syncthreads();

  // ---- phase B: pack A-fragments into LDS (bf16) ----
  // a_frag (int4 units): idx = ks*64 + ln ; holds A[row = ln&15][k = ks*32+(ln>>4)*8 ..+8]
  {
    int4* afrag = (int4*)smem;
    #pragma unroll
    for (int i = 0; i < 6; ++i) {
      int chunk = i * 256 + t;
      int ks = chunk >> 6;
      int ln = chunk & 63;
      int rr = ln & 15;
      int k0 = ks * 32 + (ln >> 4) * 8;
      int bc = rowbc[rr];
      int bcu = (bc < 0) ? rowbc[0] : bc;
      const float* src = f + (size_t)bcu * kD + k0;
      float s = rowscl[rr];
      float4 a = *(const float4*)(src);
      float4 b = *(const float4*)(src + 4);
      int4 pk;
      pk.x = bfr(a.x * s) | (bfr(a.y * s) << 16);
      pk.y = bfr(a.z * s) | (bfr(a.w * s) << 16);
      pk.z = bfr(b.x * s) | (bfr(b.y * s) << 16);
      pk.w = bfr(b.z * s) | (bfr(b.w * s) << 16);
      afrag[chunk] = pk;
    }
  }
  __syncthreads();

  // ---- K-loop: wave wq owns cols [wq*256, wq*256+256) = 16 N-tiles ----
  int wq = t >> 6, ln = t & 63;
  f32x4_t acc[16];
  #pragma unroll
  for (int nt = 0; nt < 16; ++nt) acc[nt] = (f32x4_t){0.f, 0.f, 0.f, 0.f};

  {
    const int4* afrag = (const int4*)smem;
    #pragma unroll 1
    for (int ks = 0; ks < kKS; ++ks) {
      I4S8 a; a.i = afrag[ks * 64 + ln];
      #pragma unroll
      for (int nt = 0; nt < 16; ++nt) {
        I4S8 b; b.i = pnf[(size_t)(((wq * 16 + nt) * kKS + ks) << 6) + ln];
        acc[nt] = __builtin_amdgcn_mfma_f32_16x16x32_bf16(a.s, b.s, acc[nt], 0, 0, 0);
      }
    }
  }
  __syncthreads();  // all a_frag reads done; smem becomes sims

  // ---- write tempered sims to LDS (C/D layout: col=ln&15, row=(ln>>4)*4+reg) ----
  float* sims = (float*)smem;
  #pragma unroll
  for (int nt = 0; nt < 16; ++nt) {
    #pragma unroll
    for (int reg = 0; reg < 4; ++reg) {
      int rr = (ln >> 4) * 4 + reg;
      int col = wq * 256 + nt * 16 + (ln & 15);
      sims[rr * kSimsStride + col] = acc[nt][reg] * kTauInv;
    }
  }
  __syncthreads();

  // ---- wave-local epilogue: wave wq handles rows wq*4 .. wq*4+3 ----
  for (int i = 0; i < 4; ++i) {
    int rr = wq * 4 + i;
    int bc = rowbc[rr];
    if (bc < 0) continue;
    int b = bc >> 10;
    int c = bc & (kC - 1);
    float pos = sims[rr * kSimsStride + c];
    const int* trow = targets + b * kC;
    const int* rrow = rmask + b * kC;

    float v[16]; unsigned mk[16]; int rnd[16];
    float mx = -INFINITY;
    #pragma unroll
    for (int j = 0; j < 16; ++j) {
      int e = ln + 64 * j;
      float s = sims[rr * kSimsStride + e];
      int tg = trow[e];
      float m_ = (tg == 0) ? s : -INFINITY;
      v[j] = m_; mk[j] = fkey(m_);
      mx = fmaxf(mx, m_);
      rnd[j] = rrow[e];
    }
    #pragma unroll
    for (int off = 32; off > 0; off >>= 1) mx = fmaxf(mx, __shfl_xor(mx, off, 64));

    // binary search for K_hard-th largest key (wave-local, barrier-free)
    unsigned lo = 0u, hi = 0xFFFFFFFFu;
    while (lo < hi) {
      unsigned mid = lo + ((hi - lo) >> 1);
      int c_ = 0;
      #pragma unroll
      for (int j = 0; j < 16; ++j) c_ += (mk[j] > mid) ? 1 : 0;
      #pragma unroll
      for (int off = 32; off > 0; off >>= 1) c_ += __shfl_xor(c_, off, 64);
      if (c_ >= K_hard) lo = mid + 1u; else hi = mid;
    }
    unsigned thr = lo;

    int cnt2 = 0;  // pack: n_g + (n_eq<<16)
    #pragma unroll
    for (int j = 0; j < 16; ++j) {
      cnt2 += (mk[j] > thr) ? 1 : 0;
      cnt2 += (mk[j] == thr) ? (1 << 16) : 0;
    }
    #pragma unroll
    for (int off = 32; off > 0; off >>= 1) cnt2 += __shfl_xor(cnt2, off, 64);
    int n_g = cnt2 & 0xffff;
    int n_eq = cnt2 >> 16;
    int need = K_hard - n_g;

    float ssum = 0.f;
    if (n_eq <= need) {  // common: take all == thr
      #pragma unroll
      for (int j = 0; j < 16; ++j) {
        float ev = (v[j] == -INFINITY) ? 0.f : expf(v[j] - mx);
        if (mk[j] >= thr) ssum += ev;
        if (rnd[j]) ssum += ev;
      }
    } else {  // rare tie path: lowest-index-first within == thr
      int pref = 0;
      #pragma unroll
      for (int j = 0; j < 16; ++j) {
        unsigned long long ball = __ballot(mk[j] == thr);
        int rank = pref + __popcll(ball & ((1ull << ln) - 1ull));
        bool selh = (mk[j] > thr) || (mk[j] == thr && rank < need);
        float ev = (v[j] == -INFINITY) ? 0.f : expf(v[j] - mx);
        if (selh) ssum += ev;
        if (rnd[j]) ssum += ev;
        pref += __popcll(ball);
      }
    }
    #pragma unroll
    for (int off = 32; off > 0; off >>= 1) ssum += __shfl_xor(ssum, off, 64);

    if (ln == 0) {
      float lse = mx + logf(ssum);
      float x = lse - pos;
      float pa = (x > 0.f) ? x + log1pf(expf(-x)) : log1pf(expf(x));
      atomicAdd(out, pa / (poscnt[b] * (float)B));
    }
  }
}

extern "C" void kernel_launch(void* const* d_in, const int* in_sizes, int n_in,
                              void* d_out, int out_size, void* d_ws, size_t ws_size,
                              hipStream_t stream) {
  const float* f = (const float*)d_in[0];
  const float* proto = (const float*)d_in[1];
  const int* targets = (const int*)d_in[2];
  const float* rs = (const float*)d_in[3];

  const int D = in_sizes[0] / in_sizes[2];   // 768
  const int C = in_sizes[1] / D;             // 1024
  const int B = in_sizes[2] / C;             // 16
  const int K = C - 1;
  const int K_hard = (int)(K * 0.3);         // 306
  const int K_rand = K - K_hard;             // 717

  // ws layout
  char* ws = (char*)d_ws;
  int* npos = (int*)ws;                                   // 4 B (+pad to 256)
  int* alist = (int*)(ws + 256);                          // B*C ints
  float* poscnt = (float*)(ws + 256 + 4 * B * C);         // B floats (+pad)
  int* rmask = (int*)(ws + 512 + 4 * B * C);              // B*C ints
  int4* pnf = (int4*)(ws + 1024 + 8 * B * C);             // C*D bf16 = 1.5 MB

  float* out = (float*)d_out;
  hipMemsetAsync(out, 0, sizeof(float), stream);
  hipMemsetAsync(npos, 0, sizeof(int), stream);

  proto_pack_kernel<<<C / 16, kThreads, 0, stream>>>(proto, pnf);
  rand_select_kernel<<<B, kThreads, 0, stream>>>(targets, rs, rmask, poscnt, npos, alist, K_rand);
  gemm_epi_kernel<<<(B * C) / 16, kThreads, 0, stream>>>(f, pnf, targets, rmask, poscnt, npos, alist, out, B, K_hard);
}

// Round 3
// 176.460 us; speedup vs baseline: 1.8381x; 1.1184x over previous
//
#include <hip/hip_runtime.h>
#include <cmath>

static constexpr int kC = 1024;
static constexpr int kD = 768;
static constexpr int kThreads = 256;
static constexpr float kTauInv = 10.0f;
static constexpr int kKS = kD / 32;          // 24 K-steps
static constexpr int kSimsStride = 1028;     // floats; %32==4 -> conflict-free-ish (2-way max)

typedef __attribute__((ext_vector_type(8))) short short8_t;
typedef __attribute__((ext_vector_type(4))) float f32x4_t;
union I4S8 { int4 i; short8_t s; };

__device__ __forceinline__ unsigned fkey(float f) {
  unsigned b = __float_as_uint(f);
  return (b & 0x80000000u) ? ~b : (b | 0x80000000u);
}

// round-to-nearest-even fp32 -> bf16 bits
__device__ __forceinline__ unsigned bfr(float x) {
  unsigned u = __float_as_uint(x);
  return (u + 0x7fffu + ((u >> 16) & 1u)) >> 16;
}

// ---- K1: normalize prototypes -> bf16 in MFMA B-fragment layout; also zero out/npos ----
// pnf layout (int4 units): index = (gnt*kKS + ks)*64 + ln
//   holds pn[col = gnt*16 + (ln&15)][k = ks*32 + (ln>>4)*8 .. +8]
__global__ void __launch_bounds__(kThreads) proto_pack_kernel(
    const float* __restrict__ p, int4* __restrict__ pnf,
    float* __restrict__ out, int* __restrict__ npos) {
  __shared__ float scl[16];
  int t = threadIdx.x;
  if (blockIdx.x == 0 && t == 0) { *out = 0.f; *npos = 0; }
  int n0 = blockIdx.x * 16;
  int r = t >> 4, part = t & 15;
  const float4* row4 = (const float4*)(p + (size_t)(n0 + r) * kD) + part * 12;
  float ss = 0.f;
  #pragma unroll
  for (int i = 0; i < 12; ++i) {
    float4 v = row4[i];
    ss += v.x * v.x + v.y * v.y + v.z * v.z + v.w * v.w;
  }
  #pragma unroll
  for (int off = 8; off > 0; off >>= 1) ss += __shfl_xor(ss, off, 16);
  if (part == 0) scl[r] = 1.0f / fmaxf(sqrtf(ss), 1e-12f);
  __syncthreads();
  #pragma unroll
  for (int i = 0; i < 6; ++i) {
    int chunk = i * 256 + t;
    int ks = chunk >> 6;
    int ln = chunk & 63;
    int col = ln & 15;
    int k0 = ks * 32 + (ln >> 4) * 8;
    const float* src = p + (size_t)(n0 + col) * kD + k0;
    float s = scl[col];
    float4 a = *(const float4*)(src);
    float4 b = *(const float4*)(src + 4);
    int4 pk;
    pk.x = bfr(a.x * s) | (bfr(a.y * s) << 16);
    pk.y = bfr(a.z * s) | (bfr(a.w * s) << 16);
    pk.z = bfr(b.x * s) | (bfr(b.y * s) << 16);
    pk.w = bfr(b.z * s) | (bfr(b.w * s) << 16);
    pnf[(size_t)((blockIdx.x * kKS + ks) << 6) + ln] = pk;
  }
}

// ---- K2: flags (bit0 = rand-selected, bit1 = positive) + pos counts + compacted anchor list ----
// Barrier-free after one LDS stage: every wave redundantly holds all 1024 keys (16/lane).
__global__ void __launch_bounds__(kThreads) rand_select_kernel(
    const int* __restrict__ targets, const float* __restrict__ rs,
    int* __restrict__ flags, float* __restrict__ poscnt,
    int* __restrict__ npos, int* __restrict__ alist, int K_rand) {
  __shared__ unsigned keys[kC];
  int b = blockIdx.x;
  int t = threadIdx.x;
  int wq = t >> 6, ln = t & 63;

  // phase 1: load targets/rs, build keys (positives -> fkey(-inf)=0x007FFFFF < 0x80000000 <= fkey(rs>=0))
  #pragma unroll
  for (int k = 0; k < 4; ++k) {
    int e = t + 256 * k;
    int tg = targets[b * kC + e];
    float v = (tg == 0) ? rs[b * kC + e] : -INFINITY;
    keys[e] = fkey(v);
  }
  __syncthreads();

  // phase 2: each wave grabs all 1024 keys, 16 per lane (element e = ln + 64*j)
  unsigned mk[16];
  #pragma unroll
  for (int j = 0; j < 16; ++j) mk[j] = keys[ln + 64 * j];

  // wave-local binary search for K_rand-th largest key
  unsigned lo = 0u, hi = 0xFFFFFFFFu;
  while (lo < hi) {
    unsigned mid = lo + ((hi - lo) >> 1);
    int c_ = 0;
    #pragma unroll
    for (int j = 0; j < 16; ++j) c_ += (mk[j] > mid) ? 1 : 0;
    #pragma unroll
    for (int off = 32; off > 0; off >>= 1) c_ += __shfl_xor(c_, off, 64);
    if (c_ >= K_rand) lo = mid + 1u; else hi = mid;
  }
  unsigned thr = lo;

  int cnt2 = 0;  // n_g | n_eq<<16, and positive count in parallel
  int cp = 0;
  #pragma unroll
  for (int j = 0; j < 16; ++j) {
    cnt2 += (mk[j] > thr) ? 1 : 0;
    cnt2 += (mk[j] == thr) ? (1 << 16) : 0;
    cp += (mk[j] < 0x80000000u) ? 1 : 0;
  }
  #pragma unroll
  for (int off = 32; off > 0; off >>= 1) {
    cnt2 += __shfl_xor(cnt2, off, 64);
    cp += __shfl_xor(cp, off, 64);
  }
  int n_g = cnt2 & 0xffff;
  int n_eq = cnt2 >> 16;
  int need = K_rand - n_g;
  bool take_all_eq = (n_eq <= need);

  if (t == 0) poscnt[b] = fmaxf((float)cp, 1.f);

  // wave 0: reserve alist slice with ONE atomic, scatter positives
  if (wq == 0) {
    int base = 0;
    if (ln == 0) base = atomicAdd(npos, cp);
    base = __shfl(base, 0, 64);
    int pref = 0;
    #pragma unroll
    for (int j = 0; j < 16; ++j) {
      unsigned long long ball = __ballot(mk[j] < 0x80000000u);
      if (mk[j] < 0x80000000u) {
        int rank = pref + __popcll(ball & ((1ull << ln) - 1ull));
        alist[base + rank] = b * kC + (ln + 64 * j);
      }
      pref += __popcll(ball);
    }
  }

  // each thread writes flags for its own phase-1 elements (j = wq + 4k on lane ln)
  if (take_all_eq) {
    #pragma unroll
    for (int k = 0; k < 4; ++k) {
      int j = wq + 4 * k;
      int e = ln + 64 * j;  // == t + 256*k
      unsigned kk = mk[j];
      int sel = (kk >= thr && kk >= 0x80000000u) ? 1 : 0;
      int pos = (kk < 0x80000000u) ? 2 : 0;
      flags[b * kC + e] = sel | pos;
    }
  } else {  // rare tie path: lowest-(j,ln)-index-first among == thr
    int pref = 0;
    int rankj[16];
    #pragma unroll
    for (int j = 0; j < 16; ++j) {
      unsigned long long ball = __ballot(mk[j] == thr);
      rankj[j] = pref + __popcll(ball & ((1ull << ln) - 1ull));
      pref += __popcll(ball);
    }
    #pragma unroll
    for (int k = 0; k < 4; ++k) {
      int j = wq + 4 * k;
      int e = ln + 64 * j;
      unsigned kk = mk[j];
      int sel = (kk > thr) ? 1 : ((kk == thr && rankj[j] < need) ? 1 : 0);
      int pos = (kk < 0x80000000u) ? 2 : 0;
      flags[b * kC + e] = sel | pos;
    }
  }
}

// ---- K3: fused MFMA GEMM (16 anchors x 1024 cols x 768) + wave-local epilogue ----
__global__ void __launch_bounds__(kThreads, 1) gemm_epi_kernel(
    const float* __restrict__ f, const int4* __restrict__ pnf,
    const int* __restrict__ flags, const float* __restrict__ poscnt,
    const int* __restrict__ npos_p, const int* __restrict__ alist,
    float* __restrict__ out, int B, int K_hard) {
  __shared__ __align__(16) char smem[kSimsStride * 16 * 4];  // a_frag (24KB) then sims alias
  __shared__ int rowbc[16];
  __shared__ float rowscl[16];

  int npos = *npos_p;
  int m0 = blockIdx.x * 16;
  if (m0 >= npos) return;
  int t = threadIdx.x;

  if (t < 16) rowbc[t] = (m0 + t < npos) ? alist[m0 + t] : -1;
  __syncthreads();

  // ---- phase A: row norms ----
  {
    int r = t >> 4, part = t & 15;
    int bc = rowbc[r];
    int bcu = (bc < 0) ? rowbc[0] : bc;
    const float4* f4 = (const float4*)(f + (size_t)bcu * kD) + part * 12;
    float ss = 0.f;
    #pragma unroll
    for (int i = 0; i < 12; ++i) {
      float4 v = f4[i];
      ss += v.x * v.x + v.y * v.y + v.z * v.z + v.w * v.w;
    }
    #pragma unroll
    for (int off = 8; off > 0; off >>= 1) ss += __shfl_xor(ss, off, 16);
    if (part == 0) rowscl[r] = (bc < 0) ? 0.f : 1.0f / fmaxf(sqrtf(ss), 1e-12f);
  }
  __syncthreads();

  // ---- phase B: pack A-fragments into LDS (bf16, MFMA A layout) ----
  {
    int4* afrag = (int4*)smem;
    #pragma unroll
    for (int i = 0; i < 6; ++i) {
      int chunk = i * 256 + t;
      int ks = chunk >> 6;
      int ln = chunk & 63;
      int rr = ln & 15;
      int k0 = ks * 32 + (ln >> 4) * 8;
      int bc = rowbc[rr];
      int bcu = (bc < 0) ? rowbc[0] : bc;
      const float* src = f + (size_t)bcu * kD + k0;
      float s = rowscl[rr];
      float4 a = *(const float4*)(src);
      float4 b = *(const float4*)(src + 4);
      int4 pk;
      pk.x = bfr(a.x * s) | (bfr(a.y * s) << 16);
      pk.y = bfr(a.z * s) | (bfr(a.w * s) << 16);
      pk.z = bfr(b.x * s) | (bfr(b.y * s) << 16);
      pk.w = bfr(b.z * s) | (bfr(b.w * s) << 16);
      afrag[chunk] = pk;
    }
  }
  __syncthreads();

  // ---- K-loop: wave wq owns cols [wq*256, wq*256+256); ping-pong register double-buffer ----
  int wq = t >> 6, ln = t & 63;
  f32x4_t acc[16];
  #pragma unroll
  for (int nt = 0; nt < 16; ++nt) acc[nt] = (f32x4_t){0.f, 0.f, 0.f, 0.f};

  {
    const int4* afrag = (const int4*)smem;
    const size_t ntStride = (size_t)kKS * 64;   // int4 units per N-tile group
    size_t bbase = (size_t)(wq * 16) * ntStride + ln;
    I4S8 a0, a1;
    I4S8 b0[16], b1[16];
    a0.i = afrag[ln];
    #pragma unroll
    for (int nt = 0; nt < 16; ++nt) b0[nt].i = pnf[bbase + nt * ntStride];
    #pragma unroll 1
    for (int ks = 0; ks < kKS; ks += 2) {
      a1.i = afrag[(ks + 1) * 64 + ln];
      #pragma unroll
      for (int nt = 0; nt < 16; ++nt) b1[nt].i = pnf[bbase + (ks + 1) * 64 + nt * ntStride];
      #pragma unroll
      for (int nt = 0; nt < 16; ++nt)
        acc[nt] = __builtin_amdgcn_mfma_f32_16x16x32_bf16(a0.s, b0[nt].s, acc[nt], 0, 0, 0);
      if (ks + 2 < kKS) {
        a0.i = afrag[(ks + 2) * 64 + ln];
        #pragma unroll
        for (int nt = 0; nt < 16; ++nt) b0[nt].i = pnf[bbase + (ks + 2) * 64 + nt * ntStride];
      }
      #pragma unroll
      for (int nt = 0; nt < 16; ++nt)
        acc[nt] = __builtin_amdgcn_mfma_f32_16x16x32_bf16(a1.s, b1[nt].s, acc[nt], 0, 0, 0);
    }
  }
  __syncthreads();  // a_frag reads done; smem becomes sims

  // ---- write tempered sims to LDS (C/D layout: col=ln&15, row=(ln>>4)*4+reg) ----
  float* sims = (float*)smem;
  #pragma unroll
  for (int nt = 0; nt < 16; ++nt) {
    #pragma unroll
    for (int reg = 0; reg < 4; ++reg) {
      int rr = (ln >> 4) * 4 + reg;
      int col = wq * 256 + nt * 16 + (ln & 15);
      sims[rr * kSimsStride + col] = acc[nt][reg] * kTauInv;
    }
  }
  __syncthreads();

  // ---- wave-local epilogue: wave wq handles rows wq*4 .. wq*4+3 ----
  for (int i = 0; i < 4; ++i) {
    int rr = wq * 4 + i;
    int bc = rowbc[rr];
    if (bc < 0) continue;
    int b = bc >> 10;
    int c = bc & (kC - 1);
    float pos = sims[rr * kSimsStride + c];
    const int* frow = flags + b * kC;

    int fl[16];
    #pragma unroll
    for (int j = 0; j < 16; ++j) fl[j] = frow[ln + 64 * j];

    float v[16]; unsigned mk[16];
    float mx = -INFINITY;
    #pragma unroll
    for (int j = 0; j < 16; ++j) {
      float s = sims[rr * kSimsStride + ln + 64 * j];
      float m_ = (fl[j] & 2) ? -INFINITY : s;
      v[j] = m_; mk[j] = fkey(m_);
      mx = fmaxf(mx, m_);
    }
    #pragma unroll
    for (int off = 32; off > 0; off >>= 1) mx = fmaxf(mx, __shfl_xor(mx, off, 64));

    unsigned lo = 0u, hi = 0xFFFFFFFFu;
    while (lo < hi) {
      unsigned mid = lo + ((hi - lo) >> 1);
      int c_ = 0;
      #pragma unroll
      for (int j = 0; j < 16; ++j) c_ += (mk[j] > mid) ? 1 : 0;
      #pragma unroll
      for (int off = 32; off > 0; off >>= 1) c_ += __shfl_xor(c_, off, 64);
      if (c_ >= K_hard) lo = mid + 1u; else hi = mid;
    }
    unsigned thr = lo;

    int cnt2 = 0;
    #pragma unroll
    for (int j = 0; j < 16; ++j) {
      cnt2 += (mk[j] > thr) ? 1 : 0;
      cnt2 += (mk[j] == thr) ? (1 << 16) : 0;
    }
    #pragma unroll
    for (int off = 32; off > 0; off >>= 1) cnt2 += __shfl_xor(cnt2, off, 64);
    int n_g = cnt2 & 0xffff;
    int n_eq = cnt2 >> 16;
    int need = K_hard - n_g;

    float ssum = 0.f;
    if (n_eq <= need) {
      #pragma unroll
      for (int j = 0; j < 16; ++j) {
        float ev = (v[j] == -INFINITY) ? 0.f : expf(v[j] - mx);
        if (mk[j] >= thr) ssum += ev;
        if (fl[j] & 1) ssum += ev;
      }
    } else {
      int pref = 0;
      #pragma unroll
      for (int j = 0; j < 16; ++j) {
        unsigned long long ball = __ballot(mk[j] == thr);
        int rank = pref + __popcll(ball & ((1ull << ln) - 1ull));
        bool selh = (mk[j] > thr) || (mk[j] == thr && rank < need);
        float ev = (v[j] == -INFINITY) ? 0.f : expf(v[j] - mx);
        if (selh) ssum += ev;
        if (fl[j] & 1) ssum += ev;
        pref += __popcll(ball);
      }
    }
    #pragma unroll
    for (int off = 32; off > 0; off >>= 1) ssum += __shfl_xor(ssum, off, 64);

    if (ln == 0) {
      float lse = mx + logf(ssum);
      float x = lse - pos;
      float pa = (x > 0.f) ? x + log1pf(expf(-x)) : log1pf(expf(x));
      atomicAdd(out, pa / (poscnt[b] * (float)B));
    }
  }
}

extern "C" void kernel_launch(void* const* d_in, const int* in_sizes, int n_in,
                              void* d_out, int out_size, void* d_ws, size_t ws_size,
                              hipStream_t stream) {
  const float* f = (const float*)d_in[0];
  const float* proto = (const float*)d_in[1];
  const int* targets = (const int*)d_in[2];
  const float* rs = (const float*)d_in[3];

  const int D = in_sizes[0] / in_sizes[2];   // 768
  const int C = in_sizes[1] / D;             // 1024
  const int B = in_sizes[2] / C;             // 16
  const int K = C - 1;
  const int K_hard = (int)(K * 0.3);         // 306
  const int K_rand = K - K_hard;             // 717

  // ws layout
  char* ws = (char*)d_ws;
  int* npos = (int*)ws;                                   // 4 B (+pad to 256)
  int* alist = (int*)(ws + 256);                          // B*C ints
  float* poscnt = (float*)(ws + 256 + 4 * B * C);         // B floats (+pad)
  int* flags = (int*)(ws + 512 + 8 * B * C);              // B*C ints
  int4* pnf = (int4*)(ws + 1024 + 12 * B * C);            // C*D bf16 = 1.5 MB

  float* out = (float*)d_out;

  proto_pack_kernel<<<C / 16, kThreads, 0, stream>>>(proto, pnf, out, npos);
  rand_select_kernel<<<B, kThreads, 0, stream>>>(targets, rs, flags, poscnt, npos, alist, K_rand);
  gemm_epi_kernel<<<(B * C) / 16, kThreads, 0, stream>>>(f, pnf, flags, poscnt, npos, alist, out, B, K_hard);
}

// Round 4
// 170.340 us; speedup vs baseline: 1.9042x; 1.0359x over previous
//
#include <hip/hip_runtime.h>
#include <cmath>

static constexpr int kC = 1024;
static constexpr int kD = 768;
static constexpr int kThreads = 256;
static constexpr float kTauInv = 10.0f;
static constexpr int kKS = kD / 32;        // 24 K-steps
static constexpr int kMaxPos = 128;        // per-batch anchor capacity (actual ~51)
static constexpr int kMT = kMaxPos / 16;   // 8 M-tiles per batch
static constexpr int kSS = 193;            // float4 stage stride per row (=772 floats; 2-way max LDS conflict)

typedef __attribute__((ext_vector_type(8))) short short8_t;
typedef __attribute__((ext_vector_type(4))) float f32x4_t;
union I4S8 { int4 i; short8_t s; };

__device__ __forceinline__ unsigned fkey(float f) {
  unsigned b = __float_as_uint(f);
  return (b & 0x80000000u) ? ~b : (b | 0x80000000u);
}

// round-to-nearest-even fp32 -> bf16 bits
__device__ __forceinline__ unsigned bfr(float x) {
  unsigned u = __float_as_uint(x);
  return (u + 0x7fffu + ((u >> 16) & 1u)) >> 16;
}

// ---- K1 (fused prep): blocks 0..63 pack prototypes; blocks 64..79 rand-select per batch ----
// pnf layout (int4 units): index = (gnt*kKS + ks)*64 + ln
//   holds pn[col = gnt*16 + (ln&15)][k = ks*32 + (ln>>4)*8 .. +8]
__global__ void __launch_bounds__(kThreads) prep_kernel(
    const float* __restrict__ p, const int* __restrict__ targets,
    const float* __restrict__ rs, int4* __restrict__ pnf,
    int* __restrict__ flags, int* __restrict__ cnt, float* __restrict__ poscnt,
    int* __restrict__ alist, float* __restrict__ out, int K_rand) {
  __shared__ float4 pstage[16 * kSS];
  __shared__ float scl[16];
  __shared__ unsigned keys[kC];
  int t = threadIdx.x;
  if (blockIdx.x == 0 && t == 0) *out = 0.f;

  if (blockIdx.x < 64) {
    // ---- prototype pack: 16 rows, LDS-staged ----
    int n0 = blockIdx.x * 16;
    const float4* psrc = (const float4*)p + (size_t)n0 * (kD / 4);
    #pragma unroll
    for (int i = 0; i < 12; ++i) {
      int j = t + 256 * i;
      int r = j / 192, o = j % 192;
      pstage[r * kSS + o] = psrc[j];
    }
    __syncthreads();
    {
      int r = t >> 4, part = t & 15;
      float ss = 0.f;
      #pragma unroll
      for (int i = 0; i < 12; ++i) {
        float4 v = pstage[r * kSS + part * 12 + i];
        ss += v.x * v.x + v.y * v.y + v.z * v.z + v.w * v.w;
      }
      #pragma unroll
      for (int off = 8; off > 0; off >>= 1) ss += __shfl_xor(ss, off, 16);
      if (part == 0) scl[r] = 1.0f / fmaxf(sqrtf(ss), 1e-12f);
    }
    __syncthreads();
    const float* pst = (const float*)pstage;
    #pragma unroll
    for (int i = 0; i < 6; ++i) {
      int chunk = i * 256 + t;
      int ks = chunk >> 6;
      int ln = chunk & 63;
      int col = ln & 15;
      int k0 = ks * 32 + (ln >> 4) * 8;
      const float* src = pst + col * (kSS * 4) + k0;
      float s = scl[col];
      float4 a = *(const float4*)(src);
      float4 b = *(const float4*)(src + 4);
      int4 pk;
      pk.x = bfr(a.x * s) | (bfr(a.y * s) << 16);
      pk.y = bfr(a.z * s) | (bfr(a.w * s) << 16);
      pk.z = bfr(b.x * s) | (bfr(b.y * s) << 16);
      pk.w = bfr(b.z * s) | (bfr(b.w * s) << 16);
      pnf[(size_t)((blockIdx.x * kKS + ks) << 6) + ln] = pk;
    }
  } else {
    // ---- rand select for batch b ----
    int b = blockIdx.x - 64;
    int wq = t >> 6, ln = t & 63;
    #pragma unroll
    for (int k = 0; k < 4; ++k) {
      int e = t + 256 * k;
      int tg = targets[b * kC + e];
      float v = (tg == 0) ? rs[b * kC + e] : -INFINITY;
      keys[e] = fkey(v);  // positives -> fkey(-inf) < 0x80000000 <= fkey(rs>=0)
    }
    __syncthreads();
    unsigned mk[16];
    #pragma unroll
    for (int j = 0; j < 16; ++j) mk[j] = keys[ln + 64 * j];

    unsigned lo = 0u, hi = 0xFFFFFFFFu;
    while (lo < hi) {
      unsigned mid = lo + ((hi - lo) >> 1);
      int c_ = 0;
      #pragma unroll
      for (int j = 0; j < 16; ++j) c_ += (mk[j] > mid) ? 1 : 0;
      #pragma unroll
      for (int off = 32; off > 0; off >>= 1) c_ += __shfl_xor(c_, off, 64);
      if (c_ >= K_rand) lo = mid + 1u; else hi = mid;
    }
    unsigned thr = lo;

    int cnt2 = 0, cp = 0;
    #pragma unroll
    for (int j = 0; j < 16; ++j) {
      cnt2 += (mk[j] > thr) ? 1 : 0;
      cnt2 += (mk[j] == thr) ? (1 << 16) : 0;
      cp += (mk[j] < 0x80000000u) ? 1 : 0;
    }
    #pragma unroll
    for (int off = 32; off > 0; off >>= 1) {
      cnt2 += __shfl_xor(cnt2, off, 64);
      cp += __shfl_xor(cp, off, 64);
    }
    int n_g = cnt2 & 0xffff;
    int n_eq = cnt2 >> 16;
    int need = K_rand - n_g;
    bool take_all_eq = (n_eq <= need);

    if (t == 0) {
      poscnt[b] = fmaxf((float)cp, 1.f);
      cnt[b] = (cp < kMaxPos) ? cp : kMaxPos;
    }

    // wave 0: compact positive columns into alist[b*kMaxPos ..]
    if (wq == 0) {
      int pref = 0;
      #pragma unroll
      for (int j = 0; j < 16; ++j) {
        unsigned long long ball = __ballot(mk[j] < 0x80000000u);
        if (mk[j] < 0x80000000u) {
          int rank = pref + __popcll(ball & ((1ull << ln) - 1ull));
          if (rank < kMaxPos) alist[b * kMaxPos + rank] = ln + 64 * j;
        }
        pref += __popcll(ball);
      }
    }

    if (take_all_eq) {
      #pragma unroll
      for (int k = 0; k < 4; ++k) {
        int j = wq + 4 * k;
        int e = ln + 64 * j;  // == t + 256*k
        unsigned kk = mk[j];
        int sel = (kk >= thr && kk >= 0x80000000u) ? 1 : 0;
        int pos = (kk < 0x80000000u) ? 2 : 0;
        flags[b * kC + e] = sel | pos;
      }
    } else {
      int pref = 0;
      int rankj[16];
      #pragma unroll
      for (int j = 0; j < 16; ++j) {
        unsigned long long ball = __ballot(mk[j] == thr);
        rankj[j] = pref + __popcll(ball & ((1ull << ln) - 1ull));
        pref += __popcll(ball);
      }
      #pragma unroll
      for (int k = 0; k < 4; ++k) {
        int j = wq + 4 * k;
        int e = ln + 64 * j;
        unsigned kk = mk[j];
        int sel = (kk > thr) ? 1 : ((kk == thr && rankj[j] < need) ? 1 : 0);
        int pos = (kk < 0x80000000u) ? 2 : 0;
        flags[b * kC + e] = sel | pos;
      }
    }
  }
}

// ---- K2: GEMM. grid = 16 b x 8 mt x 4 nb; block = 16 rows x 256 cols x K=768 ----
__global__ void __launch_bounds__(kThreads) gemm_kernel(
    const float* __restrict__ f, const int4* __restrict__ pnf,
    const int* __restrict__ alist, const int* __restrict__ cnt,
    float* __restrict__ simsg) {
  __shared__ float4 fstage[16 * kSS];
  __shared__ __align__(16) int4 afrag[kKS * 64];
  __shared__ int rowc[16];
  __shared__ float rowscl[16];

  int bidx = blockIdx.x;
  int b = bidx >> 5;
  int mt = (bidx >> 2) & 7;
  int nb = bidx & 3;
  int cb = cnt[b];
  if (mt * 16 >= cb) return;
  int t = threadIdx.x;

  if (t < 16) {
    int idx = mt * 16 + t;
    rowc[t] = alist[b * kMaxPos + ((idx < cb) ? idx : (cb - 1))];
  }
  __syncthreads();

  // stage the 16 f rows (coalesced) into LDS
  #pragma unroll
  for (int i = 0; i < 12; ++i) {
    int j = t + 256 * i;
    int r = j / 192, o = j % 192;
    fstage[r * kSS + o] = ((const float4*)f)[(size_t)(b * kC + rowc[r]) * (kD / 4) + o];
  }
  __syncthreads();
  {
    int r = t >> 4, part = t & 15;
    float ss = 0.f;
    #pragma unroll
    for (int i = 0; i < 12; ++i) {
      float4 v = fstage[r * kSS + part * 12 + i];
      ss += v.x * v.x + v.y * v.y + v.z * v.z + v.w * v.w;
    }
    #pragma unroll
    for (int off = 8; off > 0; off >>= 1) ss += __shfl_xor(ss, off, 16);
    if (part == 0) rowscl[r] = 1.0f / fmaxf(sqrtf(ss), 1e-12f);
  }
  __syncthreads();
  {
    const float* fst = (const float*)fstage;
    #pragma unroll
    for (int i = 0; i < 6; ++i) {
      int chunk = i * 256 + t;
      int ks = chunk >> 6;
      int ln = chunk & 63;
      int rr = ln & 15;
      int k0 = ks * 32 + (ln >> 4) * 8;
      const float* src = fst + rr * (kSS * 4) + k0;
      float s = rowscl[rr];
      float4 a = *(const float4*)(src);
      float4 b_ = *(const float4*)(src + 4);
      int4 pk;
      pk.x = bfr(a.x * s) | (bfr(a.y * s) << 16);
      pk.y = bfr(a.z * s) | (bfr(a.w * s) << 16);
      pk.z = bfr(b_.x * s) | (bfr(b_.y * s) << 16);
      pk.w = bfr(b_.z * s) | (bfr(b_.w * s) << 16);
      afrag[chunk] = pk;
    }
  }
  __syncthreads();

  // K-loop: wave wq owns 4 N-tiles (64 cols); depth-3 rotating register prefetch
  int wq = t >> 6, ln = t & 63;
  int gnt0 = nb * 16 + wq * 4;
  f32x4_t acc[4];
  #pragma unroll
  for (int nt = 0; nt < 4; ++nt) acc[nt] = (f32x4_t){0.f, 0.f, 0.f, 0.f};

  I4S8 a[3];
  I4S8 bb[3][4];
  size_t bofs[4];
  #pragma unroll
  for (int nt = 0; nt < 4; ++nt) bofs[nt] = ((size_t)(gnt0 + nt) * kKS) * 64 + ln;

  auto LOADK = [&](int ks, int s) {
    a[s].i = afrag[ks * 64 + ln];
    #pragma unroll
    for (int nt = 0; nt < 4; ++nt) bb[s][nt].i = pnf[bofs[nt] + (size_t)ks * 64];
  };
  LOADK(0, 0);
  LOADK(1, 1);
  #pragma unroll
  for (int ks = 0; ks < kKS; ++ks) {
    int s = ks % 3;
    int sn = (ks + 2) % 3;
    if (ks + 2 < kKS) LOADK(ks + 2, sn);
    #pragma unroll
    for (int nt = 0; nt < 4; ++nt)
      acc[nt] = __builtin_amdgcn_mfma_f32_16x16x32_bf16(a[s].s, bb[s][nt].s, acc[nt], 0, 0, 0);
  }

  // store tempered sims (C/D layout: col=ln&15, row=(ln>>4)*4+reg)
  float* srow = simsg + (size_t)(b * kMT + mt) * 16 * kC;
  #pragma unroll
  for (int nt = 0; nt < 4; ++nt) {
    int col = nb * 256 + wq * 64 + nt * 16 + (ln & 15);
    #pragma unroll
    for (int reg = 0; reg < 4; ++reg) {
      int rr = (ln >> 4) * 4 + reg;
      srow[rr * kC + col] = acc[nt][reg] * kTauInv;
    }
  }
}

// ---- K3: epilogue. grid = 16 b x 8 mt; wave-local top-k + LSE per anchor row ----
__global__ void __launch_bounds__(kThreads) epi_kernel(
    const float* __restrict__ simsg, const int* __restrict__ flags,
    const int* __restrict__ alist, const int* __restrict__ cnt,
    const float* __restrict__ poscnt, float* __restrict__ out,
    int B, int K_hard) {
  int b = blockIdx.x >> 3;
  int mt = blockIdx.x & 7;
  int cb = cnt[b];
  if (mt * 16 >= cb) return;
  int t = threadIdx.x;
  int wq = t >> 6, ln = t & 63;

  for (int i = 0; i < 4; ++i) {
    int rr = wq * 4 + i;
    int ridx = mt * 16 + rr;
    if (ridx >= cb) continue;
    int c = alist[b * kMaxPos + ridx];
    const float* srow = simsg + ((size_t)(b * kMT + mt) * 16 + rr) * kC;
    const int* frow = flags + b * kC;

    int fl[16];
    #pragma unroll
    for (int j = 0; j < 16; ++j) fl[j] = frow[ln + 64 * j];

    float pos = srow[c];
    float v[16]; unsigned mk[16];
    float mx = -INFINITY;
    #pragma unroll
    for (int j = 0; j < 16; ++j) {
      float s = srow[ln + 64 * j];
      float m_ = (fl[j] & 2) ? -INFINITY : s;
      v[j] = m_; mk[j] = fkey(m_);
      mx = fmaxf(mx, m_);
    }
    #pragma unroll
    for (int off = 32; off > 0; off >>= 1) mx = fmaxf(mx, __shfl_xor(mx, off, 64));

    unsigned lo = 0u, hi = 0xFFFFFFFFu;
    while (lo < hi) {
      unsigned mid = lo + ((hi - lo) >> 1);
      int c_ = 0;
      #pragma unroll
      for (int j = 0; j < 16; ++j) c_ += (mk[j] > mid) ? 1 : 0;
      #pragma unroll
      for (int off = 32; off > 0; off >>= 1) c_ += __shfl_xor(c_, off, 64);
      if (c_ >= K_hard) lo = mid + 1u; else hi = mid;
    }
    unsigned thr = lo;

    int cnt2 = 0;
    #pragma unroll
    for (int j = 0; j < 16; ++j) {
      cnt2 += (mk[j] > thr) ? 1 : 0;
      cnt2 += (mk[j] == thr) ? (1 << 16) : 0;
    }
    #pragma unroll
    for (int off = 32; off > 0; off >>= 1) cnt2 += __shfl_xor(cnt2, off, 64);
    int n_g = cnt2 & 0xffff;
    int n_eq = cnt2 >> 16;
    int need = K_hard - n_g;

    float ssum = 0.f;
    if (n_eq <= need) {
      #pragma unroll
      for (int j = 0; j < 16; ++j) {
        float ev = (v[j] == -INFINITY) ? 0.f : expf(v[j] - mx);
        if (mk[j] >= thr) ssum += ev;
        if (fl[j] & 1) ssum += ev;
      }
    } else {
      int pref = 0;
      #pragma unroll
      for (int j = 0; j < 16; ++j) {
        unsigned long long ball = __ballot(mk[j] == thr);
        int rank = pref + __popcll(ball & ((1ull << ln) - 1ull));
        bool selh = (mk[j] > thr) || (mk[j] == thr && rank < need);
        float ev = (v[j] == -INFINITY) ? 0.f : expf(v[j] - mx);
        if (selh) ssum += ev;
        if (fl[j] & 1) ssum += ev;
        pref += __popcll(ball);
      }
    }
    #pragma unroll
    for (int off = 32; off > 0; off >>= 1) ssum += __shfl_xor(ssum, off, 64);

    if (ln == 0) {
      float lse = mx + logf(ssum);
      float x = lse - pos;
      float pa = (x > 0.f) ? x + log1pf(expf(-x)) : log1pf(expf(x));
      atomicAdd(out, pa / (poscnt[b] * (float)B));
    }
  }
}

extern "C" void kernel_launch(void* const* d_in, const int* in_sizes, int n_in,
                              void* d_out, int out_size, void* d_ws, size_t ws_size,
                              hipStream_t stream) {
  const float* f = (const float*)d_in[0];
  const float* proto = (const float*)d_in[1];
  const int* targets = (const int*)d_in[2];
  const float* rs = (const float*)d_in[3];

  const int D = in_sizes[0] / in_sizes[2];   // 768
  const int C = in_sizes[1] / D;             // 1024
  const int B = in_sizes[2] / C;             // 16
  const int K = C - 1;
  const int K_hard = (int)(K * 0.3);         // 306
  const int K_rand = K - K_hard;             // 717

  // ws layout (10 MB total)
  char* ws = (char*)d_ws;
  int* cnt = (int*)ws;                         // 16 ints       @ 0
  float* poscnt = (float*)(ws + 256);          // 16 floats     @ 256
  int* alist = (int*)(ws + 512);               // 16*128 ints   @ 512 (8 KB)
  int* flags = (int*)(ws + 16384);             // B*C ints      @ 16 KB (64 KB)
  int4* pnf = (int4*)(ws + 131072);            // C*D bf16      @ 128 KB (1.5 MB)
  float* sims = (float*)(ws + 2097152);        // 2048*1024 f32 @ 2 MB (8 MB)

  float* out = (float*)d_out;

  prep_kernel<<<80, kThreads, 0, stream>>>(proto, targets, rs, pnf, flags, cnt, poscnt, alist, out, K_rand);
  gemm_kernel<<<16 * 8 * 4, kThreads, 0, stream>>>(f, pnf, alist, cnt, sims);
  epi_kernel<<<16 * 8, kThreads, 0, stream>>>(sims, flags, alist, cnt, poscnt, out, B, K_hard);
}

// Round 5
// 148.940 us; speedup vs baseline: 2.1778x; 1.1437x over previous
//
#include <hip/hip_runtime.h>
#include <cmath>

static constexpr int kC = 1024;
static constexpr int kD = 768;
static constexpr int kThreads = 256;
static constexpr float kTauInv = 10.0f;
static constexpr int kKS = kD / 32;        // 24 K-steps
static constexpr int kMaxPos = 128;        // per-batch anchor capacity (actual ~51)
static constexpr int kMT = kMaxPos / 16;   // 8 M-tiles per batch
static constexpr int kSS = 193;            // float4 stage stride per row (=772 floats; 2-way max LDS conflict)

typedef __attribute__((ext_vector_type(8))) short short8_t;
typedef __attribute__((ext_vector_type(4))) float f32x4_t;
union I4S8 { int4 i; short8_t s; };

__device__ __forceinline__ unsigned fkey(float f) {
  unsigned b = __float_as_uint(f);
  return (b & 0x80000000u) ? ~b : (b | 0x80000000u);
}

// round-to-nearest-even fp32 -> bf16 bits
__device__ __forceinline__ unsigned bfr(float x) {
  unsigned u = __float_as_uint(x);
  return (u + 0x7fffu + ((u >> 16) & 1u)) >> 16;
}

// wave-uniform count of a 16-element-per-lane predicate set via ballot+popcount
// (VALU v_cmp + scalar s_bcnt1 -- no DS-pipe shuffles)
#define BALLOT_COUNT16(expr, dst)                       \
  {                                                     \
    int c__ = 0;                                        \
    _Pragma("unroll")                                   \
    for (int j = 0; j < 16; ++j)                        \
      c__ += (int)__popcll(__ballot(expr));             \
    dst = c__;                                          \
  }

// ---- K1 (fused prep): blocks 0..63 pack prototypes; blocks 64..79 rand-select per batch ----
// pnf layout (int4 units): index = (gnt*kKS + ks)*64 + ln
//   holds pn[col = gnt*16 + (ln&15)][k = ks*32 + (ln>>4)*8 .. +8]
__global__ void __launch_bounds__(kThreads) prep_kernel(
    const float* __restrict__ p, const int* __restrict__ targets,
    const float* __restrict__ rs, int4* __restrict__ pnf,
    int* __restrict__ flags, int* __restrict__ cnt, float* __restrict__ poscnt,
    int* __restrict__ alist, float* __restrict__ out, int K_rand) {
  __shared__ float4 pstage[16 * kSS];
  __shared__ float scl[16];
  __shared__ unsigned keys[kC];
  int t = threadIdx.x;
  if (blockIdx.x == 0 && t == 0) *out = 0.f;

  if (blockIdx.x < 64) {
    // ---- prototype pack: 16 rows, LDS-staged ----
    int n0 = blockIdx.x * 16;
    const float4* psrc = (const float4*)p + (size_t)n0 * (kD / 4);
    #pragma unroll
    for (int i = 0; i < 12; ++i) {
      int j = t + 256 * i;
      int r = j / 192, o = j % 192;
      pstage[r * kSS + o] = psrc[j];
    }
    __syncthreads();
    {
      int r = t >> 4, part = t & 15;
      float ss = 0.f;
      #pragma unroll
      for (int i = 0; i < 12; ++i) {
        float4 v = pstage[r * kSS + part * 12 + i];
        ss += v.x * v.x + v.y * v.y + v.z * v.z + v.w * v.w;
      }
      #pragma unroll
      for (int off = 8; off > 0; off >>= 1) ss += __shfl_xor(ss, off, 16);
      if (part == 0) scl[r] = 1.0f / fmaxf(sqrtf(ss), 1e-12f);
    }
    __syncthreads();
    const float* pst = (const float*)pstage;
    #pragma unroll
    for (int i = 0; i < 6; ++i) {
      int chunk = i * 256 + t;
      int ks = chunk >> 6;
      int ln = chunk & 63;
      int col = ln & 15;
      int k0 = ks * 32 + (ln >> 4) * 8;
      const float* src = pst + col * (kSS * 4) + k0;
      float s = scl[col];
      float4 a = *(const float4*)(src);
      float4 b = *(const float4*)(src + 4);
      int4 pk;
      pk.x = bfr(a.x * s) | (bfr(a.y * s) << 16);
      pk.y = bfr(a.z * s) | (bfr(a.w * s) << 16);
      pk.z = bfr(b.x * s) | (bfr(b.y * s) << 16);
      pk.w = bfr(b.z * s) | (bfr(b.w * s) << 16);
      pnf[(size_t)((blockIdx.x * kKS + ks) << 6) + ln] = pk;
    }
  } else {
    // ---- rand select for batch b ----
    int b = blockIdx.x - 64;
    int wq = t >> 6, ln = t & 63;
    #pragma unroll
    for (int k = 0; k < 4; ++k) {
      int e = t + 256 * k;
      int tg = targets[b * kC + e];
      float v = (tg == 0) ? rs[b * kC + e] : -INFINITY;
      keys[e] = fkey(v);  // positives -> fkey(-inf) < 0x80000000 <= fkey(rs>=0)
    }
    __syncthreads();
    unsigned mk[16];
    #pragma unroll
    for (int j = 0; j < 16; ++j) mk[j] = keys[ln + 64 * j];

    // ballot-based binary search for K_rand-th largest key
    unsigned lo = 0u, hi = 0xFFFFFFFFu;
    while (lo < hi) {
      unsigned mid = lo + ((hi - lo) >> 1);
      int c_;
      BALLOT_COUNT16(mk[j] > mid, c_);
      if (c_ >= K_rand) lo = mid + 1u; else hi = mid;
    }
    unsigned thr = lo;

    int n_g, n_eq, cp;
    BALLOT_COUNT16(mk[j] > thr, n_g);
    BALLOT_COUNT16(mk[j] == thr, n_eq);
    BALLOT_COUNT16(mk[j] < 0x80000000u, cp);
    int need = K_rand - n_g;
    bool take_all_eq = (n_eq <= need);

    if (t == 0) {
      poscnt[b] = fmaxf((float)cp, 1.f);
      cnt[b] = (cp < kMaxPos) ? cp : kMaxPos;
    }

    // wave 0: compact positive columns into alist[b*kMaxPos ..]
    if (wq == 0) {
      int pref = 0;
      #pragma unroll
      for (int j = 0; j < 16; ++j) {
        unsigned long long ball = __ballot(mk[j] < 0x80000000u);
        if (mk[j] < 0x80000000u) {
          int rank = pref + __popcll(ball & ((1ull << ln) - 1ull));
          if (rank < kMaxPos) alist[b * kMaxPos + rank] = ln + 64 * j;
        }
        pref += __popcll(ball);
      }
    }

    if (take_all_eq) {
      #pragma unroll
      for (int k = 0; k < 4; ++k) {
        int j = wq + 4 * k;
        int e = ln + 64 * j;  // == t + 256*k
        unsigned kk = mk[j];
        int sel = (kk >= thr && kk >= 0x80000000u) ? 1 : 0;
        int pos = (kk < 0x80000000u) ? 2 : 0;
        flags[b * kC + e] = sel | pos;
      }
    } else {
      int pref = 0;
      int rankj[16];
      #pragma unroll
      for (int j = 0; j < 16; ++j) {
        unsigned long long ball = __ballot(mk[j] == thr);
        rankj[j] = pref + __popcll(ball & ((1ull << ln) - 1ull));
        pref += __popcll(ball);
      }
      #pragma unroll
      for (int k = 0; k < 4; ++k) {
        int j = wq + 4 * k;
        int e = ln + 64 * j;
        unsigned kk = mk[j];
        int sel = (kk > thr) ? 1 : ((kk == thr && rankj[j] < need) ? 1 : 0);
        int pos = (kk < 0x80000000u) ? 2 : 0;
        flags[b * kC + e] = sel | pos;
      }
    }
  }
}

// ---- K2: GEMM. grid = 16 b x 8 mt x 4 nb; block = 16 rows x 256 cols x K=768 ----
__global__ void __launch_bounds__(kThreads) gemm_kernel(
    const float* __restrict__ f, const int4* __restrict__ pnf,
    const int* __restrict__ alist, const int* __restrict__ cnt,
    float* __restrict__ simsg) {
  __shared__ float4 fstage[16 * kSS];
  __shared__ __align__(16) int4 afrag[kKS * 64];
  __shared__ int rowc[16];
  __shared__ float rowscl[16];

  int bidx = blockIdx.x;
  int b = bidx >> 5;
  int mt = (bidx >> 2) & 7;
  int nb = bidx & 3;
  int cb = cnt[b];
  if (mt * 16 >= cb) return;
  int t = threadIdx.x;

  if (t < 16) {
    int idx = mt * 16 + t;
    rowc[t] = alist[b * kMaxPos + ((idx < cb) ? idx : (cb - 1))];
  }
  __syncthreads();

  // stage the 16 f rows (coalesced) into LDS
  #pragma unroll
  for (int i = 0; i < 12; ++i) {
    int j = t + 256 * i;
    int r = j / 192, o = j % 192;
    fstage[r * kSS + o] = ((const float4*)f)[(size_t)(b * kC + rowc[r]) * (kD / 4) + o];
  }
  __syncthreads();
  {
    int r = t >> 4, part = t & 15;
    float ss = 0.f;
    #pragma unroll
    for (int i = 0; i < 12; ++i) {
      float4 v = fstage[r * kSS + part * 12 + i];
      ss += v.x * v.x + v.y * v.y + v.z * v.z + v.w * v.w;
    }
    #pragma unroll
    for (int off = 8; off > 0; off >>= 1) ss += __shfl_xor(ss, off, 16);
    if (part == 0) rowscl[r] = 1.0f / fmaxf(sqrtf(ss), 1e-12f);
  }
  __syncthreads();
  {
    const float* fst = (const float*)fstage;
    #pragma unroll
    for (int i = 0; i < 6; ++i) {
      int chunk = i * 256 + t;
      int ks = chunk >> 6;
      int ln = chunk & 63;
      int rr = ln & 15;
      int k0 = ks * 32 + (ln >> 4) * 8;
      const float* src = fst + rr * (kSS * 4) + k0;
      float s = rowscl[rr];
      float4 a = *(const float4*)(src);
      float4 b_ = *(const float4*)(src + 4);
      int4 pk;
      pk.x = bfr(a.x * s) | (bfr(a.y * s) << 16);
      pk.y = bfr(a.z * s) | (bfr(a.w * s) << 16);
      pk.z = bfr(b_.x * s) | (bfr(b_.y * s) << 16);
      pk.w = bfr(b_.z * s) | (bfr(b_.w * s) << 16);
      afrag[chunk] = pk;
    }
  }
  __syncthreads();

  // K-loop: wave wq owns 4 N-tiles (64 cols); depth-3 rotating register prefetch
  int wq = t >> 6, ln = t & 63;
  int gnt0 = nb * 16 + wq * 4;
  f32x4_t acc[4];
  #pragma unroll
  for (int nt = 0; nt < 4; ++nt) acc[nt] = (f32x4_t){0.f, 0.f, 0.f, 0.f};

  I4S8 a[3];
  I4S8 bb[3][4];
  size_t bofs[4];
  #pragma unroll
  for (int nt = 0; nt < 4; ++nt) bofs[nt] = ((size_t)(gnt0 + nt) * kKS) * 64 + ln;

  auto LOADK = [&](int ks, int s) {
    a[s].i = afrag[ks * 64 + ln];
    #pragma unroll
    for (int nt = 0; nt < 4; ++nt) bb[s][nt].i = pnf[bofs[nt] + (size_t)ks * 64];
  };
  LOADK(0, 0);
  LOADK(1, 1);
  #pragma unroll
  for (int ks = 0; ks < kKS; ++ks) {
    int s = ks % 3;
    int sn = (ks + 2) % 3;
    if (ks + 2 < kKS) LOADK(ks + 2, sn);
    #pragma unroll
    for (int nt = 0; nt < 4; ++nt)
      acc[nt] = __builtin_amdgcn_mfma_f32_16x16x32_bf16(a[s].s, bb[s][nt].s, acc[nt], 0, 0, 0);
  }

  // store tempered sims (C/D layout: col=ln&15, row=(ln>>4)*4+reg)
  float* srow = simsg + (size_t)(b * kMT + mt) * 16 * kC;
  #pragma unroll
  for (int nt = 0; nt < 4; ++nt) {
    int col = nb * 256 + wq * 64 + nt * 16 + (ln & 15);
    #pragma unroll
    for (int reg = 0; reg < 4; ++reg) {
      int rr = (ln >> 4) * 4 + reg;
      srow[rr * kC + col] = acc[nt][reg] * kTauInv;
    }
  }
}

// ---- K3: epilogue. grid = 16 b x 8 mt; ballot-based wave-local top-k + LSE per anchor row ----
__global__ void __launch_bounds__(kThreads) epi_kernel(
    const float* __restrict__ simsg, const int* __restrict__ flags,
    const int* __restrict__ alist, const int* __restrict__ cnt,
    const float* __restrict__ poscnt, float* __restrict__ out,
    int B, int K_hard) {
  int b = blockIdx.x >> 3;
  int mt = blockIdx.x & 7;
  int cb = cnt[b];
  if (mt * 16 >= cb) return;
  int t = threadIdx.x;
  int wq = t >> 6, ln = t & 63;

  // flags are per-batch: identical for every row this wave handles -- load ONCE
  const int* frow = flags + b * kC;
  int fl[16];
  #pragma unroll
  for (int j = 0; j < 16; ++j) fl[j] = frow[ln + 64 * j];

  for (int i = 0; i < 4; ++i) {
    int rr = wq * 4 + i;
    int ridx = mt * 16 + rr;
    if (ridx >= cb) continue;
    int c = alist[b * kMaxPos + ridx];
    const float* srow = simsg + ((size_t)(b * kMT + mt) * 16 + rr) * kC;

    float pos = srow[c];
    float v[16]; unsigned mk[16];
    float mx = -INFINITY;
    #pragma unroll
    for (int j = 0; j < 16; ++j) {
      float s = srow[ln + 64 * j];
      float m_ = (fl[j] & 2) ? -INFINITY : s;
      v[j] = m_; mk[j] = fkey(m_);
      mx = fmaxf(mx, m_);
    }
    #pragma unroll
    for (int off = 32; off > 0; off >>= 1) mx = fmaxf(mx, __shfl_xor(mx, off, 64));

    // ballot-based binary search for K_hard-th largest key (no DS-pipe in the loop)
    unsigned lo = 0u, hi = 0xFFFFFFFFu;
    while (lo < hi) {
      unsigned mid = lo + ((hi - lo) >> 1);
      int c_;
      BALLOT_COUNT16(mk[j] > mid, c_);
      if (c_ >= K_hard) lo = mid + 1u; else hi = mid;
    }
    unsigned thr = lo;

    int n_g, n_eq;
    BALLOT_COUNT16(mk[j] > thr, n_g);
    BALLOT_COUNT16(mk[j] == thr, n_eq);
    int need = K_hard - n_g;

    float ssum = 0.f;
    if (n_eq <= need) {
      #pragma unroll
      for (int j = 0; j < 16; ++j) {
        float ev = (v[j] == -INFINITY) ? 0.f : expf(v[j] - mx);
        if (mk[j] >= thr) ssum += ev;
        if (fl[j] & 1) ssum += ev;
      }
    } else {
      int pref = 0;
      #pragma unroll
      for (int j = 0; j < 16; ++j) {
        unsigned long long ball = __ballot(mk[j] == thr);
        int rank = pref + __popcll(ball & ((1ull << ln) - 1ull));
        bool selh = (mk[j] > thr) || (mk[j] == thr && rank < need);
        float ev = (v[j] == -INFINITY) ? 0.f : expf(v[j] - mx);
        if (selh) ssum += ev;
        if (fl[j] & 1) ssum += ev;
        pref += __popcll(ball);
      }
    }
    #pragma unroll
    for (int off = 32; off > 0; off >>= 1) ssum += __shfl_xor(ssum, off, 64);

    if (ln == 0) {
      float lse = mx + logf(ssum);
      float x = lse - pos;
      float pa = (x > 0.f) ? x + log1pf(expf(-x)) : log1pf(expf(x));
      atomicAdd(out, pa / (poscnt[b] * (float)B));
    }
  }
}

extern "C" void kernel_launch(void* const* d_in, const int* in_sizes, int n_in,
                              void* d_out, int out_size, void* d_ws, size_t ws_size,
                              hipStream_t stream) {
  const float* f = (const float*)d_in[0];
  const float* proto = (const float*)d_in[1];
  const int* targets = (const int*)d_in[2];
  const float* rs = (const float*)d_in[3];

  const int D = in_sizes[0] / in_sizes[2];   // 768
  const int C = in_sizes[1] / D;             // 1024
  const int B = in_sizes[2] / C;             // 16
  const int K = C - 1;
  const int K_hard = (int)(K * 0.3);         // 306
  const int K_rand = K - K_hard;             // 717

  // ws layout (10 MB total)
  char* ws = (char*)d_ws;
  int* cnt = (int*)ws;                         // 16 ints       @ 0
  float* poscnt = (float*)(ws + 256);          // 16 floats     @ 256
  int* alist = (int*)(ws + 512);               // 16*128 ints   @ 512 (8 KB)
  int* flags = (int*)(ws + 16384);             // B*C ints      @ 16 KB (64 KB)
  int4* pnf = (int4*)(ws + 131072);            // C*D bf16      @ 128 KB (1.5 MB)
  float* sims = (float*)(ws + 2097152);        // 2048*1024 f32 @ 2 MB (8 MB)

  float* out = (float*)d_out;

  prep_kernel<<<80, kThreads, 0, stream>>>(proto, targets, rs, pnf, flags, cnt, poscnt, alist, out, K_rand);
  gemm_kernel<<<16 * 8 * 4, kThreads, 0, stream>>>(f, pnf, alist, cnt, sims);
  epi_kernel<<<16 * 8, kThreads, 0, stream>>>(sims, flags, alist, cnt, poscnt, out, B, K_hard);
}

// Round 6
// 128.667 us; speedup vs baseline: 2.5209x; 1.1576x over previous
//
#include <hip/hip_runtime.h>
#include <cmath>

static constexpr int kC = 1024;
static constexpr int kD = 768;
static constexpr int kThreads = 256;
static constexpr float kTauInv = 10.0f;
static constexpr int kKS = kD / 32;        // 24 K-steps
static constexpr int kMaxPos = 128;        // per-batch anchor capacity (actual ~51)
static constexpr int kMT = kMaxPos / 16;   // 8 M-tiles per batch
static constexpr int kSS = 193;            // float4 stage stride per row (=772 floats; 2-way max LDS conflict)

typedef __attribute__((ext_vector_type(8))) short short8_t;
typedef __attribute__((ext_vector_type(4))) float f32x4_t;
union I4S8 { int4 i; short8_t s; };

__device__ __forceinline__ unsigned fkey(float f) {
  unsigned b = __float_as_uint(f);
  return (b & 0x80000000u) ? ~b : (b | 0x80000000u);
}

// round-to-nearest-even fp32 -> bf16 bits
__device__ __forceinline__ unsigned bfr(float x) {
  unsigned u = __float_as_uint(x);
  return (u + 0x7fffu + ((u >> 16) & 1u)) >> 16;
}

// wave-uniform count of a 16-element-per-lane predicate set via ballot+popcount
// (VALU v_cmp + scalar s_bcnt1 -- no DS-pipe shuffles)
#define BALLOT_COUNT16(expr, dst)                       \
  {                                                     \
    int c__ = 0;                                        \
    _Pragma("unroll")                                   \
    for (int j = 0; j < 16; ++j)                        \
      c__ += (int)__popcll(__ballot(expr));             \
    dst = c__;                                          \
  }

// ---- K1 (fused prep): blocks 0..63 pack prototypes; blocks 64..79 rand-select per batch ----
// pnf layout (int4 units): index = (gnt*kKS + ks)*64 + ln
//   holds pn[col = gnt*16 + (ln&15)][k = ks*32 + (ln>>4)*8 .. +8]
__global__ void __launch_bounds__(kThreads) prep_kernel(
    const float* __restrict__ p, const int* __restrict__ targets,
    const float* __restrict__ rs, int4* __restrict__ pnf,
    int* __restrict__ flags, int* __restrict__ cnt, float* __restrict__ poscnt,
    int* __restrict__ alist, float* __restrict__ out, int K_rand) {
  __shared__ float4 pstage[16 * kSS];
  __shared__ float scl[16];
  __shared__ unsigned keys[kC];
  int t = threadIdx.x;
  if (blockIdx.x == 0 && t == 0) *out = 0.f;

  if (blockIdx.x < 64) {
    // ---- prototype pack: 16 rows, LDS-staged ----
    int n0 = blockIdx.x * 16;
    const float4* psrc = (const float4*)p + (size_t)n0 * (kD / 4);
    #pragma unroll
    for (int i = 0; i < 12; ++i) {
      int j = t + 256 * i;
      int r = j / 192, o = j % 192;
      pstage[r * kSS + o] = psrc[j];
    }
    __syncthreads();
    {
      int r = t >> 4, part = t & 15;
      float ss = 0.f;
      #pragma unroll
      for (int i = 0; i < 12; ++i) {
        float4 v = pstage[r * kSS + part * 12 + i];
        ss += v.x * v.x + v.y * v.y + v.z * v.z + v.w * v.w;
      }
      #pragma unroll
      for (int off = 8; off > 0; off >>= 1) ss += __shfl_xor(ss, off, 16);
      if (part == 0) scl[r] = 1.0f / fmaxf(sqrtf(ss), 1e-12f);
    }
    __syncthreads();
    const float* pst = (const float*)pstage;
    #pragma unroll
    for (int i = 0; i < 6; ++i) {
      int chunk = i * 256 + t;
      int ks = chunk >> 6;
      int ln = chunk & 63;
      int col = ln & 15;
      int k0 = ks * 32 + (ln >> 4) * 8;
      const float* src = pst + col * (kSS * 4) + k0;
      float s = scl[col];
      float4 a = *(const float4*)(src);
      float4 b = *(const float4*)(src + 4);
      int4 pk;
      pk.x = bfr(a.x * s) | (bfr(a.y * s) << 16);
      pk.y = bfr(a.z * s) | (bfr(a.w * s) << 16);
      pk.z = bfr(b.x * s) | (bfr(b.y * s) << 16);
      pk.w = bfr(b.z * s) | (bfr(b.w * s) << 16);
      pnf[(size_t)((blockIdx.x * kKS + ks) << 6) + ln] = pk;
    }
  } else {
    // ---- rand select for batch b ----
    int b = blockIdx.x - 64;
    int wq = t >> 6, ln = t & 63;
    #pragma unroll
    for (int k = 0; k < 4; ++k) {
      int e = t + 256 * k;
      int tg = targets[b * kC + e];
      float v = (tg == 0) ? rs[b * kC + e] : -INFINITY;
      keys[e] = fkey(v);  // positives -> fkey(-inf) < 0x80000000 <= fkey(rs>=0)
    }
    __syncthreads();
    unsigned mk[16];
    #pragma unroll
    for (int j = 0; j < 16; ++j) mk[j] = keys[ln + 64 * j];

    // ballot-based binary search for K_rand-th largest key
    unsigned lo = 0u, hi = 0xFFFFFFFFu;
    while (lo < hi) {
      unsigned mid = lo + ((hi - lo) >> 1);
      int c_;
      BALLOT_COUNT16(mk[j] > mid, c_);
      if (c_ >= K_rand) lo = mid + 1u; else hi = mid;
    }
    unsigned thr = lo;

    int n_g, n_eq, cp;
    BALLOT_COUNT16(mk[j] > thr, n_g);
    BALLOT_COUNT16(mk[j] == thr, n_eq);
    BALLOT_COUNT16(mk[j] < 0x80000000u, cp);
    int need = K_rand - n_g;
    bool take_all_eq = (n_eq <= need);

    if (t == 0) {
      poscnt[b] = fmaxf((float)cp, 1.f);
      cnt[b] = (cp < kMaxPos) ? cp : kMaxPos;
    }

    // wave 0: compact positive columns into alist[b*kMaxPos ..]
    if (wq == 0) {
      int pref = 0;
      #pragma unroll
      for (int j = 0; j < 16; ++j) {
        unsigned long long ball = __ballot(mk[j] < 0x80000000u);
        if (mk[j] < 0x80000000u) {
          int rank = pref + __popcll(ball & ((1ull << ln) - 1ull));
          if (rank < kMaxPos) alist[b * kMaxPos + rank] = ln + 64 * j;
        }
        pref += __popcll(ball);
      }
    }

    if (take_all_eq) {
      #pragma unroll
      for (int k = 0; k < 4; ++k) {
        int j = wq + 4 * k;
        int e = ln + 64 * j;  // == t + 256*k
        unsigned kk = mk[j];
        int sel = (kk >= thr && kk >= 0x80000000u) ? 1 : 0;
        int pos = (kk < 0x80000000u) ? 2 : 0;
        flags[b * kC + e] = sel | pos;
      }
    } else {
      int pref = 0;
      int rankj[16];
      #pragma unroll
      for (int j = 0; j < 16; ++j) {
        unsigned long long ball = __ballot(mk[j] == thr);
        rankj[j] = pref + __popcll(ball & ((1ull << ln) - 1ull));
        pref += __popcll(ball);
      }
      #pragma unroll
      for (int k = 0; k < 4; ++k) {
        int j = wq + 4 * k;
        int e = ln + 64 * j;
        unsigned kk = mk[j];
        int sel = (kk > thr) ? 1 : ((kk == thr && rankj[j] < need) ? 1 : 0);
        int pos = (kk < 0x80000000u) ? 2 : 0;
        flags[b * kC + e] = sel | pos;
      }
    }
  }
}

// ---- K2: GEMM. grid = 16 b x 8 mt x 4 nb; block = 16 rows x 256 cols x K=768 ----
__global__ void __launch_bounds__(kThreads) gemm_kernel(
    const float* __restrict__ f, const int4* __restrict__ pnf,
    const int* __restrict__ alist, const int* __restrict__ cnt,
    float* __restrict__ simsg) {
  __shared__ float4 fstage[16 * kSS];
  __shared__ __align__(16) int4 afrag[kKS * 64];
  __shared__ int rowc[16];
  __shared__ float rowscl[16];

  int bidx = blockIdx.x;
  int b = bidx >> 5;
  int mt = (bidx >> 2) & 7;
  int nb = bidx & 3;
  int cb = cnt[b];
  if (mt * 16 >= cb) return;
  int t = threadIdx.x;

  if (t < 16) {
    int idx = mt * 16 + t;
    rowc[t] = alist[b * kMaxPos + ((idx < cb) ? idx : (cb - 1))];
  }
  __syncthreads();

  // stage the 16 f rows (coalesced) into LDS
  #pragma unroll
  for (int i = 0; i < 12; ++i) {
    int j = t + 256 * i;
    int r = j / 192, o = j % 192;
    fstage[r * kSS + o] = ((const float4*)f)[(size_t)(b * kC + rowc[r]) * (kD / 4) + o];
  }
  __syncthreads();
  {
    int r = t >> 4, part = t & 15;
    float ss = 0.f;
    #pragma unroll
    for (int i = 0; i < 12; ++i) {
      float4 v = fstage[r * kSS + part * 12 + i];
      ss += v.x * v.x + v.y * v.y + v.z * v.z + v.w * v.w;
    }
    #pragma unroll
    for (int off = 8; off > 0; off >>= 1) ss += __shfl_xor(ss, off, 16);
    if (part == 0) rowscl[r] = 1.0f / fmaxf(sqrtf(ss), 1e-12f);
  }
  __syncthreads();
  {
    const float* fst = (const float*)fstage;
    #pragma unroll
    for (int i = 0; i < 6; ++i) {
      int chunk = i * 256 + t;
      int ks = chunk >> 6;
      int ln = chunk & 63;
      int rr = ln & 15;
      int k0 = ks * 32 + (ln >> 4) * 8;
      const float* src = fst + rr * (kSS * 4) + k0;
      float s = rowscl[rr];
      float4 a = *(const float4*)(src);
      float4 b_ = *(const float4*)(src + 4);
      int4 pk;
      pk.x = bfr(a.x * s) | (bfr(a.y * s) << 16);
      pk.y = bfr(a.z * s) | (bfr(a.w * s) << 16);
      pk.z = bfr(b_.x * s) | (bfr(b_.y * s) << 16);
      pk.w = bfr(b_.z * s) | (bfr(b_.w * s) << 16);
      afrag[chunk] = pk;
    }
  }
  __syncthreads();

  // K-loop: wave wq owns 4 N-tiles (64 cols); depth-3 rotating register prefetch
  int wq = t >> 6, ln = t & 63;
  int gnt0 = nb * 16 + wq * 4;
  f32x4_t acc[4];
  #pragma unroll
  for (int nt = 0; nt < 4; ++nt) acc[nt] = (f32x4_t){0.f, 0.f, 0.f, 0.f};

  I4S8 a[3];
  I4S8 bb[3][4];
  size_t bofs[4];
  #pragma unroll
  for (int nt = 0; nt < 4; ++nt) bofs[nt] = ((size_t)(gnt0 + nt) * kKS) * 64 + ln;

  auto LOADK = [&](int ks, int s) {
    a[s].i = afrag[ks * 64 + ln];
    #pragma unroll
    for (int nt = 0; nt < 4; ++nt) bb[s][nt].i = pnf[bofs[nt] + (size_t)ks * 64];
  };
  LOADK(0, 0);
  LOADK(1, 1);
  #pragma unroll
  for (int ks = 0; ks < kKS; ++ks) {
    int s = ks % 3;
    int sn = (ks + 2) % 3;
    if (ks + 2 < kKS) LOADK(ks + 2, sn);
    #pragma unroll
    for (int nt = 0; nt < 4; ++nt)
      acc[nt] = __builtin_amdgcn_mfma_f32_16x16x32_bf16(a[s].s, bb[s][nt].s, acc[nt], 0, 0, 0);
  }

  // store tempered sims (C/D layout: col=ln&15, row=(ln>>4)*4+reg)
  float* srow = simsg + (size_t)(b * kMT + mt) * 16 * kC;
  #pragma unroll
  for (int nt = 0; nt < 4; ++nt) {
    int col = nb * 256 + wq * 64 + nt * 16 + (ln & 15);
    #pragma unroll
    for (int reg = 0; reg < 4; ++reg) {
      int rr = (ln >> 4) * 4 + reg;
      srow[rr * kC + col] = acc[nt][reg] * kTauInv;
    }
  }
}

// ---- K3: epilogue. grid = 16 b x 32 groups; ONE anchor row per wave ----
__global__ void __launch_bounds__(kThreads) epi_kernel(
    const float* __restrict__ simsg, const int* __restrict__ flags,
    const int* __restrict__ alist, const int* __restrict__ cnt,
    const float* __restrict__ poscnt, float* __restrict__ out,
    int B, int K_hard) {
  int b = blockIdx.x >> 5;
  int g4 = blockIdx.x & 31;           // group of 4 rows
  int cb = cnt[b];
  if (g4 * 4 >= cb) return;
  int t = threadIdx.x;
  int wq = t >> 6, ln = t & 63;

  int ridx = g4 * 4 + wq;             // this wave's anchor row
  if (ridx >= cb) return;
  int mt = ridx >> 4;
  int rr = ridx & 15;
  int c = alist[b * kMaxPos + ridx];
  const float* srow = simsg + ((size_t)(b * kMT + mt) * 16 + rr) * kC;
  const int* frow = flags + b * kC;

  int fl[16];
  #pragma unroll
  for (int j = 0; j < 16; ++j) fl[j] = frow[ln + 64 * j];

  float pos = srow[c];
  float v[16]; unsigned mk[16];
  float mx = -INFINITY;
  #pragma unroll
  for (int j = 0; j < 16; ++j) {
    float s = srow[ln + 64 * j];
    float m_ = (fl[j] & 2) ? -INFINITY : s;
    v[j] = m_; mk[j] = fkey(m_);
    mx = fmaxf(mx, m_);
  }
  #pragma unroll
  for (int off = 32; off > 0; off >>= 1) mx = fmaxf(mx, __shfl_xor(mx, off, 64));

  // ballot-based binary search for K_hard-th largest key (no DS-pipe in the loop)
  unsigned lo = 0u, hi = 0xFFFFFFFFu;
  while (lo < hi) {
    unsigned mid = lo + ((hi - lo) >> 1);
    int c_;
    BALLOT_COUNT16(mk[j] > mid, c_);
    if (c_ >= K_hard) lo = mid + 1u; else hi = mid;
  }
  unsigned thr = lo;

  int n_g, n_eq;
  BALLOT_COUNT16(mk[j] > thr, n_g);
  BALLOT_COUNT16(mk[j] == thr, n_eq);
  int need = K_hard - n_g;

  float ssum = 0.f;
  if (n_eq <= need) {
    #pragma unroll
    for (int j = 0; j < 16; ++j) {
      float ev = (v[j] == -INFINITY) ? 0.f : __expf(v[j] - mx);
      if (mk[j] >= thr) ssum += ev;
      if (fl[j] & 1) ssum += ev;
    }
  } else {
    int pref = 0;
    #pragma unroll
    for (int j = 0; j < 16; ++j) {
      unsigned long long ball = __ballot(mk[j] == thr);
      int rank = pref + __popcll(ball & ((1ull << ln) - 1ull));
      bool selh = (mk[j] > thr) || (mk[j] == thr && rank < need);
      float ev = (v[j] == -INFINITY) ? 0.f : __expf(v[j] - mx);
      if (selh) ssum += ev;
      if (fl[j] & 1) ssum += ev;
      pref += __popcll(ball);
    }
  }
  #pragma unroll
  for (int off = 32; off > 0; off >>= 1) ssum += __shfl_xor(ssum, off, 64);

  if (ln == 0) {
    float lse = mx + logf(ssum);
    float x = lse - pos;
    float pa = (x > 0.f) ? x + log1pf(__expf(-x)) : log1pf(__expf(x));
    atomicAdd(out, pa / (poscnt[b] * (float)B));
  }
}

extern "C" void kernel_launch(void* const* d_in, const int* in_sizes, int n_in,
                              void* d_out, int out_size, void* d_ws, size_t ws_size,
                              hipStream_t stream) {
  const float* f = (const float*)d_in[0];
  const float* proto = (const float*)d_in[1];
  const int* targets = (const int*)d_in[2];
  const float* rs = (const float*)d_in[3];

  const int D = in_sizes[0] / in_sizes[2];   // 768
  const int C = in_sizes[1] / D;             // 1024
  const int B = in_sizes[2] / C;             // 16
  const int K = C - 1;
  const int K_hard = (int)(K * 0.3);         // 306
  const int K_rand = K - K_hard;             // 717

  // ws layout (10 MB total)
  char* ws = (char*)d_ws;
  int* cnt = (int*)ws;                         // 16 ints       @ 0
  float* poscnt = (float*)(ws + 256);          // 16 floats     @ 256
  int* alist = (int*)(ws + 512);               // 16*128 ints   @ 512 (8 KB)
  int* flags = (int*)(ws + 16384);             // B*C ints      @ 16 KB (64 KB)
  int4* pnf = (int4*)(ws + 131072);            // C*D bf16      @ 128 KB (1.5 MB)
  float* sims = (float*)(ws + 2097152);        // 2048*1024 f32 @ 2 MB (8 MB)

  float* out = (float*)d_out;

  prep_kernel<<<80, kThreads, 0, stream>>>(proto, targets, rs, pnf, flags, cnt, poscnt, alist, out, K_rand);
  gemm_kernel<<<16 * 8 * 4, kThreads, 0, stream>>>(f, pnf, alist, cnt, sims);
  epi_kernel<<<16 * 32, kThreads, 0, stream>>>(sims, flags, alist, cnt, poscnt, out, B, K_hard);
}